// Round 15
// baseline (227.325 us; speedup 1.0000x reference)
//
#include <hip/hip_runtime.h>
#include <hip/hip_bf16.h>

#define N_NODES 10000
#define M_PAD   10112          // 79 * 128
#define DIM     256
#define HID     512
#define KDIM    512            // K for both GEMMs (2*DIM == HID == 512)
#define N_EDGE  320000
#define ELL_W   128            // max degree capacity (mean 32, sigma 5.7)
#define NTILES  316            // 79 M-tiles x 4 N-tiles
#define NBLK    256            // fused-kernel grid (guaranteed co-resident)

typedef __attribute__((ext_vector_type(4))) float  f32x4;
typedef __attribute__((ext_vector_type(8))) __bf16 bf16x8;

// round-to-nearest-even f32 -> bf16 bits
__device__ __forceinline__ unsigned short f2bf(float f) {
    union { float f; unsigned int u; } v; v.f = f;
    unsigned int r = v.u + 0x7FFFu + ((v.u >> 16) & 1u);
    return (unsigned short)(r >> 16);
}
// bf16 bits -> f32 (exact)
__device__ __forceinline__ float bf2f(unsigned short u) {
    union { unsigned int i; float f; } v; v.i = ((unsigned int)u) << 16;
    return v.f;
}

// async global->LDS DMA, 16B per lane; LDS dest = wave-uniform base + lane*16
__device__ __forceinline__ void gload16(const void* g, void* l) {
    __builtin_amdgcn_global_load_lds(
        (const __attribute__((address_space(1))) void*)g,
        (__attribute__((address_space(3))) void*)l, 16, 0, 0);
}

// ---------------------------------------------------------------------------
// zero deg[0..10240) and the fused-kernel barrier counters
// ---------------------------------------------------------------------------
__global__ void k_zero(int* __restrict__ deg, int* __restrict__ cnt) {
    int i = blockIdx.x * 256 + threadIdx.x;
    if (i < 10240) deg[i] = 0;
    if (i < 8)     cnt[i] = 0;
}

// ---------------------------------------------------------------------------
// LDS-tiled 64x64 transpose+cast: Wt[n][k] = bf16(W[k][n]); both sides coalesced.
// ---------------------------------------------------------------------------
__device__ __forceinline__ void wtrans(const float* __restrict__ W,
                                       unsigned short* __restrict__ Wt,
                                       int tb, float (*tile)[65]) {
    const int t  = threadIdx.x;
    const int kb = (tb >> 3) * 64, nb = (tb & 7) * 64;
    const int r    = t >> 2;             // 64 rows
    const int cseg = (t & 3) * 16;       // 4 col-segments of 16
    const float* src = W + (size_t)(kb + r) * 512 + nb + cseg;
    #pragma unroll
    for (int j = 0; j < 4; ++j)
        *(f32x4*)&tile[r][cseg + 4 * j] = *(const f32x4*)(src + 4 * j);
    __syncthreads();
    unsigned short* dst = Wt + (size_t)(nb + r) * 512 + kb + cseg;
    #pragma unroll
    for (int j = 0; j < 4; ++j) {
        ushort4 o;
        o.x = f2bf(tile[cseg + 4 * j + 0][r]);
        o.y = f2bf(tile[cseg + 4 * j + 1][r]);
        o.z = f2bf(tile[cseg + 4 * j + 2][r]);
        o.w = f2bf(tile[cseg + 4 * j + 3][r]);
        *(ushort4*)(dst + 4 * j) = o;
    }
}

// ---------------------------------------------------------------------------
// Fused prep: blockIdx ranges dispatch 4 independent jobs
// ---------------------------------------------------------------------------
__global__ void k_prep(const int* __restrict__ esrc, const int* __restrict__ edst,
                       const float* __restrict__ eval,
                       int* __restrict__ deg, int2* __restrict__ ell,
                       const float* __restrict__ x, unsigned short* __restrict__ cat,
                       const float* __restrict__ Wc, unsigned short* __restrict__ Wct,
                       const float* __restrict__ W1, unsigned short* __restrict__ W1t) {
    __shared__ float tile[64][65];
    int b = blockIdx.x;
    if (b < 1250) {
        int e = b * 256 + threadIdx.x;
        if (e < N_EDGE) {
            int d = edst[e];
            int slot = atomicAdd(&deg[d], 1);
            if (slot < ELL_W)   // safety clamp; never triggers for this input
                ell[(size_t)d * ELL_W + slot] = make_int2(esrc[e], __float_as_int(eval[e]));
        }
    } else if (b < 3750) {
        int t  = (b - 1250) * 256 + threadIdx.x;   // < 640000 exactly
        int n  = t >> 6;
        int c4 = (t & 63) * 4;
        f32x4 v = *(const f32x4*)(x + (size_t)n * DIM + c4);
        ushort4 o;
        o.x = f2bf(v.x); o.y = f2bf(v.y); o.z = f2bf(v.z); o.w = f2bf(v.w);
        *(ushort4*)(cat + (size_t)n * 2 * DIM + c4) = o;
    } else if (b < 3814) {
        wtrans(Wc, Wct, b - 3750, tile);
    } else {
        wtrans(W1, W1t, b - 3814, tile);
    }
}

// ---------------------------------------------------------------------------
// Aggregate: one wave per node; readlane-broadcast ELL records, 8 gathers in
// flight into 8 accumulators.
// ---------------------------------------------------------------------------
__global__ void k_agg(const int* __restrict__ deg, const int2* __restrict__ ell,
                      unsigned short* __restrict__ cat) {
    int wid  = (blockIdx.x * blockDim.x + threadIdx.x) >> 6;
    int lane = threadIdx.x & 63;
    if (wid >= N_NODES) return;
    int cnt = deg[wid];
    if (cnt > ELL_W) cnt = ELL_W;
    const int2* row = ell + (size_t)wid * ELL_W;
    int c4 = lane * 4;
    f32x4 a0 = {0.f,0.f,0.f,0.f}, a1 = a0, a2 = a0, a3 = a0;
    f32x4 a4 = a0, a5 = a0, a6 = a0, a7 = a0;
    for (int base = 0; base < cnt; base += 64) {
        int m = cnt - base;
        if (m > 64) m = 64;
        int2 my = make_int2(0, 0);
        if (lane < m) my = row[base + lane];
        int j = 0;
        for (; j + 8 <= m; j += 8) {
            int   s0 = __builtin_amdgcn_readlane(my.x, j);
            float v0 = __int_as_float(__builtin_amdgcn_readlane(my.y, j));
            int   s1 = __builtin_amdgcn_readlane(my.x, j + 1);
            float v1 = __int_as_float(__builtin_amdgcn_readlane(my.y, j + 1));
            int   s2 = __builtin_amdgcn_readlane(my.x, j + 2);
            float v2 = __int_as_float(__builtin_amdgcn_readlane(my.y, j + 2));
            int   s3 = __builtin_amdgcn_readlane(my.x, j + 3);
            float v3 = __int_as_float(__builtin_amdgcn_readlane(my.y, j + 3));
            int   s4 = __builtin_amdgcn_readlane(my.x, j + 4);
            float v4 = __int_as_float(__builtin_amdgcn_readlane(my.y, j + 4));
            int   s5 = __builtin_amdgcn_readlane(my.x, j + 5);
            float v5 = __int_as_float(__builtin_amdgcn_readlane(my.y, j + 5));
            int   s6 = __builtin_amdgcn_readlane(my.x, j + 6);
            float v6 = __int_as_float(__builtin_amdgcn_readlane(my.y, j + 6));
            int   s7 = __builtin_amdgcn_readlane(my.x, j + 7);
            float v7 = __int_as_float(__builtin_amdgcn_readlane(my.y, j + 7));
            ushort4 q0 = *(const ushort4*)(cat + (size_t)s0 * 2 * DIM + c4);
            ushort4 q1 = *(const ushort4*)(cat + (size_t)s1 * 2 * DIM + c4);
            ushort4 q2 = *(const ushort4*)(cat + (size_t)s2 * 2 * DIM + c4);
            ushort4 q3 = *(const ushort4*)(cat + (size_t)s3 * 2 * DIM + c4);
            ushort4 q4 = *(const ushort4*)(cat + (size_t)s4 * 2 * DIM + c4);
            ushort4 q5 = *(const ushort4*)(cat + (size_t)s5 * 2 * DIM + c4);
            ushort4 q6 = *(const ushort4*)(cat + (size_t)s6 * 2 * DIM + c4);
            ushort4 q7 = *(const ushort4*)(cat + (size_t)s7 * 2 * DIM + c4);
            a0.x += v0 * bf2f(q0.x); a0.y += v0 * bf2f(q0.y);
            a0.z += v0 * bf2f(q0.z); a0.w += v0 * bf2f(q0.w);
            a1.x += v1 * bf2f(q1.x); a1.y += v1 * bf2f(q1.y);
            a1.z += v1 * bf2f(q1.z); a1.w += v1 * bf2f(q1.w);
            a2.x += v2 * bf2f(q2.x); a2.y += v2 * bf2f(q2.y);
            a2.z += v2 * bf2f(q2.z); a2.w += v2 * bf2f(q2.w);
            a3.x += v3 * bf2f(q3.x); a3.y += v3 * bf2f(q3.y);
            a3.z += v3 * bf2f(q3.z); a3.w += v3 * bf2f(q3.w);
            a4.x += v4 * bf2f(q4.x); a4.y += v4 * bf2f(q4.y);
            a4.z += v4 * bf2f(q4.z); a4.w += v4 * bf2f(q4.w);
            a5.x += v5 * bf2f(q5.x); a5.y += v5 * bf2f(q5.y);
            a5.z += v5 * bf2f(q5.z); a5.w += v5 * bf2f(q5.w);
            a6.x += v6 * bf2f(q6.x); a6.y += v6 * bf2f(q6.y);
            a6.z += v6 * bf2f(q6.z); a6.w += v6 * bf2f(q6.w);
            a7.x += v7 * bf2f(q7.x); a7.y += v7 * bf2f(q7.y);
            a7.z += v7 * bf2f(q7.z); a7.w += v7 * bf2f(q7.w);
        }
        for (; j < m; ++j) {
            int   s0 = __builtin_amdgcn_readlane(my.x, j);
            float v0 = __int_as_float(__builtin_amdgcn_readlane(my.y, j));
            ushort4 q0 = *(const ushort4*)(cat + (size_t)s0 * 2 * DIM + c4);
            a0.x += v0 * bf2f(q0.x); a0.y += v0 * bf2f(q0.y);
            a0.z += v0 * bf2f(q0.z); a0.w += v0 * bf2f(q0.w);
        }
    }
    ushort4 o;
    o.x = f2bf(((a0.x + a1.x) + (a2.x + a3.x)) + ((a4.x + a5.x) + (a6.x + a7.x)));
    o.y = f2bf(((a0.y + a1.y) + (a2.y + a3.y)) + ((a4.y + a5.y) + (a6.y + a7.y)));
    o.z = f2bf(((a0.z + a1.z) + (a2.z + a3.z)) + ((a4.z + a5.z) + (a6.z + a7.z)));
    o.w = f2bf(((a0.w + a1.w) + (a2.w + a3.w)) + ((a4.w + a5.w) + (a6.w + a7.w)));
    *(ushort4*)(cat + (size_t)wid * 2 * DIM + DIM + c4) = o;
}

// ---------------------------------------------------------------------------
// GEMM tile body (R14-verbatim): global_load_lds DMA, linear [128][64] LDS,
// XOR-swizzle pair, double-buffered, one __syncthreads per K-step.
// ---------------------------------------------------------------------------
#define STAGE(buf, kt) { \
    _Pragma("unroll") \
    for (int i = 0; i < 4; ++i) { \
        gload16(pA + (size_t)i * 8 * KDIM + (kt) * 64, &As[buf][ldsbase + i * 512]); \
        gload16(pB + (size_t)i * 8 * KDIM + (kt) * 64, &Bs[buf][ldsbase + i * 512]); \
    } }

template <int MODE>
__device__ void gemm_tile(int tile,
                          const unsigned short* __restrict__ A,
                          const unsigned short* __restrict__ Bt,
                          const float* __restrict__ bias,
                          const float* __restrict__ pa,
                          const float* __restrict__ w2,
                          unsigned short* __restrict__ hout,
                          float* __restrict__ part,
                          unsigned short (*As)[8192],
                          unsigned short (*Bs)[8192]) {
    __syncthreads();                          // LDS safe to overwrite (prev tile/phase)

    const int t    = threadIdx.x;
    const int lane = t & 63;
    const int w    = t >> 6;
    const int wr   = w >> 1, wc = w & 1;
    const int tn   = tile & 3;                // 4 N-tiles
    const int tm   = tile >> 2;               // 79 M-tiles
    const int gm0  = tm * 128, gn0 = tn * 128;

    const int srow = w * 32 + (lane >> 3);
    const int lc   = (lane & 7) ^ (lane >> 3);
    const unsigned short* pA = A  + (size_t)(gm0 + srow) * KDIM + lc * 8;
    const unsigned short* pB = Bt + (size_t)(gn0 + srow) * KDIM + lc * 8;
    const int ldsbase = w * 2048;             // elements; +i*512 per instr

    const int r15 = lane & 15;
    const int hi  = lane >> 4;
    const int x7  = r15 & 7;

    f32x4 acc[4][4] = {};

    STAGE(0, 0);
    __syncthreads();                          // buf0 DMA complete

    #pragma unroll
    for (int ks = 0; ks < 8; ++ks) {
        const int cur = ks & 1;
        if (ks < 7) STAGE(cur ^ 1, ks + 1);   // async; lands during MFMA phase
        #pragma unroll
        for (int kk = 0; kk < 2; ++kk) {
            const int pc = ((kk * 4 + hi) ^ x7) * 8;   // swizzled chunk -> elems
            bf16x8 af[4], bf[4];
            #pragma unroll
            for (int m = 0; m < 4; ++m)
                af[m] = *(const bf16x8*)&As[cur][(wr * 64 + m * 16 + r15) * 64 + pc];
            #pragma unroll
            for (int n = 0; n < 4; ++n)
                bf[n] = *(const bf16x8*)&Bs[cur][(wc * 64 + n * 16 + r15) * 64 + pc];
            #pragma unroll
            for (int m = 0; m < 4; ++m)
                #pragma unroll
                for (int n = 0; n < 4; ++n)
                    acc[m][n] = __builtin_amdgcn_mfma_f32_16x16x32_bf16(af[m], bf[n], acc[m][n], 0, 0, 0);
        }
        if (ks < 7) __syncthreads();          // next buf ready; prev reads done
    }

    const int rq = lane >> 4;                // C row quad
    if (MODE == 0) {
        #pragma unroll
        for (int n = 0; n < 4; ++n) {
            int c = gn0 + wc * 64 + n * 16 + r15;
            float b = bias[c];
            #pragma unroll
            for (int m = 0; m < 4; ++m) {
                #pragma unroll
                for (int i = 0; i < 4; ++i) {
                    int row = gm0 + wr * 64 + m * 16 + rq * 4 + i;
                    float v = acc[m][n][i] + b;
                    v = v > 0.f ? v : 0.f;   // NaN/garbage from pad rows -> 0
                    hout[(size_t)row * HID + c] = f2bf(v);
                }
            }
        }
    } else {
        float rsum[4][4] = {};
        #pragma unroll
        for (int n = 0; n < 4; ++n) {
            int c = gn0 + wc * 64 + n * 16 + r15;
            float b = bias[c];
            float a = pa[c];
            float wv = w2[c];
            #pragma unroll
            for (int m = 0; m < 4; ++m)
                #pragma unroll
                for (int i = 0; i < 4; ++i) {
                    float v = acc[m][n][i] + b;
                    v = v > 0.f ? v : a * v;
                    rsum[m][i] += v * wv;
                }
        }
        #pragma unroll
        for (int m = 0; m < 4; ++m)
            #pragma unroll
            for (int i = 0; i < 4; ++i) {
                float s = rsum[m][i];
                s += __shfl_xor(s, 1);
                s += __shfl_xor(s, 2);
                s += __shfl_xor(s, 4);
                s += __shfl_xor(s, 8);
                if (r15 == 0) {
                    int row = gm0 + wr * 64 + m * 16 + rq * 4 + i;
                    part[(size_t)(tn * 2 + wc) * M_PAD + row] = s;
                }
            }
    }
}

// device-scope inter-block barrier (G16 pattern): release writeback by all
// threads, arrive via agent-scope atomic, acquire-invalidate on the spin.
__device__ __forceinline__ void gbar(int* cnt) {
    __threadfence();                          // flush this block's stores (L2 wb)
    __syncthreads();
    if (threadIdx.x == 0) {
        __hip_atomic_fetch_add(cnt, 1, __ATOMIC_ACQ_REL, __HIP_MEMORY_SCOPE_AGENT);
        while (__hip_atomic_load(cnt, __ATOMIC_ACQUIRE, __HIP_MEMORY_SCOPE_AGENT) < NBLK)
            __builtin_amdgcn_s_sleep(8);
    }
    __syncthreads();
}

// ---------------------------------------------------------------------------
// Fused MLP: gemm1 (relu) -> barrier -> gemm2+PReLU+GEMV-partials -> barrier
// -> partial reduce to pred. Grid NBLK=256 (1 block/CU guaranteed resident),
// each block grid-strides the 316 tiles.
// ---------------------------------------------------------------------------
__global__ __launch_bounds__(256)
void k_mlp(const unsigned short* __restrict__ cat,
           const unsigned short* __restrict__ Wct, const float* __restrict__ bc,
           const unsigned short* __restrict__ W1t, const float* __restrict__ b1,
           const float* __restrict__ pa, const float* __restrict__ W2,
           const float* __restrict__ b2,
           unsigned short* __restrict__ h, float* __restrict__ part,
           float* __restrict__ pred, int* __restrict__ cnt) {
    __shared__ unsigned short As[2][8192];
    __shared__ unsigned short Bs[2][8192];
    const int bid = blockIdx.x;

    for (int tile = bid; tile < NTILES; tile += NBLK)
        gemm_tile<0>(tile, cat, Wct, bc, nullptr, nullptr, h, nullptr, As, Bs);
    gbar(&cnt[0]);                            // h visible device-wide

    for (int tile = bid; tile < NTILES; tile += NBLK)
        gemm_tile<1>(tile, h, W1t, b1, pa, W2, nullptr, part, As, Bs);
    gbar(&cnt[1]);                            // partials visible device-wide

    int row = bid * 256 + threadIdx.x;
    if (row < N_NODES) {
        float s = b2[0];
        #pragma unroll
        for (int j = 0; j < 8; ++j) s += part[(size_t)j * M_PAD + row];
        pred[row] = s;
    }
}

extern "C" void kernel_launch(void* const* d_in, const int* in_sizes, int n_in,
                              void* d_out, int out_size, void* d_ws, size_t ws_size,
                              hipStream_t stream) {
    const float* x    = (const float*)d_in[0];
    const int*   esrc = (const int*)  d_in[1];
    const int*   edst = (const int*)  d_in[2];
    const float* eval = (const float*)d_in[3];
    const float* Wc   = (const float*)d_in[4];
    const float* bc   = (const float*)d_in[5];
    const float* W1   = (const float*)d_in[6];
    const float* b1   = (const float*)d_in[7];
    const float* pa   = (const float*)d_in[8];
    const float* W2   = (const float*)d_in[9];
    const float* b2   = (const float*)d_in[10];
    float* pred = (float*)d_out;

    // workspace layout (16B-aligned), total ~32.6 MB
    char* w = (char*)d_ws;
    int*            deg   = (int*)w;                               //     40,960 B
    int2*           ell   = (int2*)(w + 40960);                    // 10,485,760 B
    unsigned short* cat   = (unsigned short*)(w + 10526720);       // 10,354,688 B (M_PAD x 512)
    unsigned short* Wct   = (unsigned short*)(w + 20881408);       //    524,288 B
    unsigned short* W1t   = (unsigned short*)(w + 21405696);       //    524,288 B
    unsigned short* h     = (unsigned short*)(w + 21929984);       // 10,354,688 B (M_PAD x 512)
    float*          partb = (float*)(w + 32284672);                //    323,584 B (8 x M_PAD)
    int*            cnt   = (int*)(w + 32608256);                  //         32 B

    // ---- zero slot counters + barrier counters ----
    k_zero<<<41, 256, 0, stream>>>(deg, cnt);

    // ---- fused prep (ELL scatter + cat_x + LDS-tiled weight transposes) ----
    k_prep<<<3878, 256, 0, stream>>>(esrc, edst, eval, deg, ell, x, cat, Wc, Wct, W1, W1t);

    // ---- gather-aggregate into cat second half ----
    k_agg<<<(N_NODES * 64 + 255) / 256, 256, 0, stream>>>(deg, ell, cat);

    // ---- fused gemm1 -> gemm2+GEMV -> reduce (one kernel, 2 device barriers) ----
    k_mlp<<<NBLK, 256, 0, stream>>>(cat, Wct, bc, W1t, b1, pa, W2, b2,
                                    h, partb, pred, cnt);
}

// Round 16
// 85.297 us; speedup vs baseline: 2.6651x; 2.6651x over previous
//
#include <hip/hip_runtime.h>
#include <hip/hip_bf16.h>

#define N_NODES 10000
#define M_PAD   10112          // 79 * 128
#define DIM     256
#define HID     512
#define KDIM    512            // K for both GEMMs (2*DIM == HID == 512)
#define N_EDGE  320000
#define ELL_W   128            // max degree capacity (mean 32, sigma 5.7)

typedef __attribute__((ext_vector_type(4))) float  f32x4;
typedef __attribute__((ext_vector_type(8))) __bf16 bf16x8;

// round-to-nearest-even f32 -> bf16 bits
__device__ __forceinline__ unsigned short f2bf(float f) {
    union { float f; unsigned int u; } v; v.f = f;
    unsigned int r = v.u + 0x7FFFu + ((v.u >> 16) & 1u);
    return (unsigned short)(r >> 16);
}
// bf16 bits -> f32 (exact)
__device__ __forceinline__ float bf2f(unsigned short u) {
    union { unsigned int i; float f; } v; v.i = ((unsigned int)u) << 16;
    return v.f;
}

// ---------------------------------------------------------------------------
// zero deg[0..10240)
// ---------------------------------------------------------------------------
__global__ void k_zero(int* __restrict__ deg) {
    int i = blockIdx.x * 256 + threadIdx.x;
    if (i < 10240) deg[i] = 0;
}

// ---------------------------------------------------------------------------
// Fused prep: blockIdx ranges dispatch 4 independent jobs
//   [0,1250)      : ELL scatter  ell[d][slot] = (src, val)   (slot via atomic)
//   [1250,3750)   : cat[n][0..255] = bf16(x[n][*])
//   [3750,4774)   : Wct = bf16(Wc^T)
//   [4774,5798)   : W1t = bf16(W1^T)
// ---------------------------------------------------------------------------
__global__ void k_prep(const int* __restrict__ esrc, const int* __restrict__ edst,
                       const float* __restrict__ eval,
                       int* __restrict__ deg, int2* __restrict__ ell,
                       const float* __restrict__ x, unsigned short* __restrict__ cat,
                       const float* __restrict__ Wc, unsigned short* __restrict__ Wct,
                       const float* __restrict__ W1, unsigned short* __restrict__ W1t) {
    int b = blockIdx.x;
    if (b < 1250) {
        int e = b * 256 + threadIdx.x;
        if (e < N_EDGE) {
            int d = edst[e];
            int slot = atomicAdd(&deg[d], 1);
            if (slot < ELL_W)   // safety clamp; never triggers for this input
                ell[(size_t)d * ELL_W + slot] = make_int2(esrc[e], __float_as_int(eval[e]));
        }
    } else if (b < 3750) {
        int t  = (b - 1250) * 256 + threadIdx.x;   // < 640000 exactly
        int n  = t >> 6;
        int c4 = (t & 63) * 4;
        f32x4 v = *(const f32x4*)(x + (size_t)n * DIM + c4);
        ushort4 o;
        o.x = f2bf(v.x); o.y = f2bf(v.y); o.z = f2bf(v.z); o.w = f2bf(v.w);
        *(ushort4*)(cat + (size_t)n * 2 * DIM + c4) = o;
    } else if (b < 4774) {
        int t = (b - 3750) * 256 + threadIdx.x;
        int k = t >> 9, n = t & 511;
        Wct[(size_t)n * 512 + k] = f2bf(Wc[(size_t)k * 512 + n]);
    } else {
        int t = (b - 4774) * 256 + threadIdx.x;
        int k = t >> 9, n = t & 511;
        W1t[(size_t)n * 512 + k] = f2bf(W1[(size_t)k * 512 + n]);
    }
}

// ---------------------------------------------------------------------------
// Aggregate: one wave per node. Lane l preloads ELL record l (coalesced 8B),
// readlane-broadcasts it; 4 row gathers in flight into 4 accumulators.
// ---------------------------------------------------------------------------
__global__ void k_agg(const int* __restrict__ deg, const int2* __restrict__ ell,
                      unsigned short* __restrict__ cat) {
    int wid  = (blockIdx.x * blockDim.x + threadIdx.x) >> 6;
    int lane = threadIdx.x & 63;
    if (wid >= N_NODES) return;
    int cnt = deg[wid];
    if (cnt > ELL_W) cnt = ELL_W;
    const int2* row = ell + (size_t)wid * ELL_W;
    int c4 = lane * 4;
    f32x4 a0 = {0.f,0.f,0.f,0.f}, a1 = a0, a2 = a0, a3 = a0;
    for (int base = 0; base < cnt; base += 64) {
        int m = cnt - base;
        if (m > 64) m = 64;
        int2 my = make_int2(0, 0);
        if (lane < m) my = row[base + lane];
        int j = 0;
        for (; j + 4 <= m; j += 4) {
            int   s0 = __builtin_amdgcn_readlane(my.x, j);
            float v0 = __int_as_float(__builtin_amdgcn_readlane(my.y, j));
            int   s1 = __builtin_amdgcn_readlane(my.x, j + 1);
            float v1 = __int_as_float(__builtin_amdgcn_readlane(my.y, j + 1));
            int   s2 = __builtin_amdgcn_readlane(my.x, j + 2);
            float v2 = __int_as_float(__builtin_amdgcn_readlane(my.y, j + 2));
            int   s3 = __builtin_amdgcn_readlane(my.x, j + 3);
            float v3 = __int_as_float(__builtin_amdgcn_readlane(my.y, j + 3));
            ushort4 q0 = *(const ushort4*)(cat + (size_t)s0 * 2 * DIM + c4);
            ushort4 q1 = *(const ushort4*)(cat + (size_t)s1 * 2 * DIM + c4);
            ushort4 q2 = *(const ushort4*)(cat + (size_t)s2 * 2 * DIM + c4);
            ushort4 q3 = *(const ushort4*)(cat + (size_t)s3 * 2 * DIM + c4);
            a0.x += v0 * bf2f(q0.x); a0.y += v0 * bf2f(q0.y);
            a0.z += v0 * bf2f(q0.z); a0.w += v0 * bf2f(q0.w);
            a1.x += v1 * bf2f(q1.x); a1.y += v1 * bf2f(q1.y);
            a1.z += v1 * bf2f(q1.z); a1.w += v1 * bf2f(q1.w);
            a2.x += v2 * bf2f(q2.x); a2.y += v2 * bf2f(q2.y);
            a2.z += v2 * bf2f(q2.z); a2.w += v2 * bf2f(q2.w);
            a3.x += v3 * bf2f(q3.x); a3.y += v3 * bf2f(q3.y);
            a3.z += v3 * bf2f(q3.z); a3.w += v3 * bf2f(q3.w);
        }
        for (; j < m; ++j) {
            int   s0 = __builtin_amdgcn_readlane(my.x, j);
            float v0 = __int_as_float(__builtin_amdgcn_readlane(my.y, j));
            ushort4 q0 = *(const ushort4*)(cat + (size_t)s0 * 2 * DIM + c4);
            a0.x += v0 * bf2f(q0.x); a0.y += v0 * bf2f(q0.y);
            a0.z += v0 * bf2f(q0.z); a0.w += v0 * bf2f(q0.w);
        }
    }
    ushort4 o;
    o.x = f2bf((a0.x + a1.x) + (a2.x + a3.x));
    o.y = f2bf((a0.y + a1.y) + (a2.y + a3.y));
    o.z = f2bf((a0.z + a1.z) + (a2.z + a3.z));
    o.w = f2bf((a0.w + a1.w) + (a2.w + a3.w));
    *(ushort4*)(cat + (size_t)wid * 2 * DIM + DIM + c4) = o;
}

// ---------------------------------------------------------------------------
// LDS-tiled GEMM, double-buffered: ONE barrier per K-step.
//   step ks: issue loads for ks+1 -> regs; MFMA on buf[cur]; regs -> buf[cur^1];
//            barrier.
// 128x128 tile per block, 4 waves (2x2), 64x64 per wave, +8 pad (no conflicts).
// MODE 0: relu(acc+bias) -> bf16 hout.
// MODE 1: prelu(acc+bias) dot w2, column-reduced -> part[8][M_PAD] (fused GEMV).
// ---------------------------------------------------------------------------
#define LDSW 72   // 64 + 8 pad, elements

#define LOAD4(dst, p) { dst[0] = *(const f32x4*)(p); dst[1] = *(const f32x4*)((p) + 8); \
                        dst[2] = *(const f32x4*)((p) + 16); dst[3] = *(const f32x4*)((p) + 24); }
#define STORE4(p, src) { *(f32x4*)(p) = src[0]; *(f32x4*)((p) + 8) = src[1]; \
                         *(f32x4*)((p) + 16) = src[2]; *(f32x4*)((p) + 24) = src[3]; }

template <int MODE>
__global__ __launch_bounds__(256)
void k_gemm128(const unsigned short* __restrict__ A,
               const unsigned short* __restrict__ Bt,
               const float* __restrict__ bias,
               const float* __restrict__ pa,
               const float* __restrict__ w2,
               unsigned short* __restrict__ hout,
               float* __restrict__ part) {
    __shared__ unsigned short As[2][128 * LDSW];
    __shared__ unsigned short Bs[2][128 * LDSW];

    const int t    = threadIdx.x;
    const int lane = t & 63;
    const int w    = t >> 6;
    const int wr   = w >> 1, wc = w & 1;
    const int tn   = blockIdx.x & 3;          // 4 N-tiles
    const int tm   = blockIdx.x >> 2;         // 79 M-tiles
    const int gm0  = tm * 128, gn0 = tn * 128;

    // staging map: thread t loads 64 B of row (t>>1), col half (t&1)*32
    const int srow = t >> 1;
    const int scol = (t & 1) * 32;
    const unsigned short* gA = A  + (size_t)(gm0 + srow) * KDIM + scol;
    const unsigned short* gB = Bt + (size_t)(gn0 + srow) * KDIM + scol;
    const int woff = srow * LDSW + scol;

    const int r15 = lane & 15;
    const int kf  = (lane >> 4) * 8;

    f32x4 acc[4][4] = {};
    f32x4 va[4], vb[4];

    LOAD4(va, gA);                            // K-tile 0
    LOAD4(vb, gB);
    STORE4(&As[0][woff], va);
    STORE4(&Bs[0][woff], vb);
    __syncthreads();                          // buf0 ready

    #pragma unroll
    for (int ks = 0; ks < 8; ++ks) {
        const int cur = ks & 1;
        if (ks < 7) {                         // next tile's loads fly under MFMAs
            gA += 64; gB += 64;
            LOAD4(va, gA);
            LOAD4(vb, gB);
        }
        #pragma unroll
        for (int kk = 0; kk < 2; ++kk) {
            bf16x8 af[4], bf[4];
            #pragma unroll
            for (int m = 0; m < 4; ++m)
                af[m] = *(const bf16x8*)&As[cur][(wr * 64 + m * 16 + r15) * LDSW + kk * 32 + kf];
            #pragma unroll
            for (int n = 0; n < 4; ++n)
                bf[n] = *(const bf16x8*)&Bs[cur][(wc * 64 + n * 16 + r15) * LDSW + kk * 32 + kf];
            #pragma unroll
            for (int m = 0; m < 4; ++m)
                #pragma unroll
                for (int n = 0; n < 4; ++n)
                    acc[m][n] = __builtin_amdgcn_mfma_f32_16x16x32_bf16(af[m], bf[n], acc[m][n], 0, 0, 0);
        }
        if (ks < 7) {                         // write next tile to the OTHER buf
            STORE4(&As[cur ^ 1][woff], va);
            STORE4(&Bs[cur ^ 1][woff], vb);
            __syncthreads();                  // next buf ready (prev reads done)
        }
    }

    const int rq = lane >> 4;                // C row quad
    if (MODE == 0) {
        #pragma unroll
        for (int n = 0; n < 4; ++n) {
            int c = gn0 + wc * 64 + n * 16 + r15;
            float b = bias[c];
            #pragma unroll
            for (int m = 0; m < 4; ++m) {
                #pragma unroll
                for (int i = 0; i < 4; ++i) {
                    int row = gm0 + wr * 64 + m * 16 + rq * 4 + i;
                    float v = acc[m][n][i] + b;
                    v = v > 0.f ? v : 0.f;   // NaN/garbage from pad rows -> 0
                    hout[(size_t)row * HID + c] = f2bf(v);
                }
            }
        }
    } else {
        float rsum[4][4] = {};
        #pragma unroll
        for (int n = 0; n < 4; ++n) {
            int c = gn0 + wc * 64 + n * 16 + r15;
            float b = bias[c];
            float a = pa[c];
            float wv = w2[c];
            #pragma unroll
            for (int m = 0; m < 4; ++m)
                #pragma unroll
                for (int i = 0; i < 4; ++i) {
                    float v = acc[m][n][i] + b;
                    v = v > 0.f ? v : a * v;
                    rsum[m][i] += v * wv;
                }
        }
        // reduce over the 16 column-lanes; lane&15==0 holds the sum
        #pragma unroll
        for (int m = 0; m < 4; ++m)
            #pragma unroll
            for (int i = 0; i < 4; ++i) {
                float s = rsum[m][i];
                s += __shfl_xor(s, 1);
                s += __shfl_xor(s, 2);
                s += __shfl_xor(s, 4);
                s += __shfl_xor(s, 8);
                if (r15 == 0) {
                    int row = gm0 + wr * 64 + m * 16 + rq * 4 + i;
                    part[(size_t)(tn * 2 + wc) * M_PAD + row] = s;
                }
            }
    }
}

// ---------------------------------------------------------------------------
// pred[row] = sum_j part[j][row] + b2
// ---------------------------------------------------------------------------
__global__ void k_vout(const float* __restrict__ part, const float* __restrict__ b2,
                       float* __restrict__ pred) {
    int row = blockIdx.x * blockDim.x + threadIdx.x;
    if (row >= N_NODES) return;
    float s = b2[0];
    #pragma unroll
    for (int j = 0; j < 8; ++j) s += part[(size_t)j * M_PAD + row];
    pred[row] = s;
}

extern "C" void kernel_launch(void* const* d_in, const int* in_sizes, int n_in,
                              void* d_out, int out_size, void* d_ws, size_t ws_size,
                              hipStream_t stream) {
    const float* x    = (const float*)d_in[0];
    const int*   esrc = (const int*)  d_in[1];
    const int*   edst = (const int*)  d_in[2];
    const float* eval = (const float*)d_in[3];
    const float* Wc   = (const float*)d_in[4];
    const float* bc   = (const float*)d_in[5];
    const float* W1   = (const float*)d_in[6];
    const float* b1   = (const float*)d_in[7];
    const float* pa   = (const float*)d_in[8];
    const float* W2   = (const float*)d_in[9];
    const float* b2   = (const float*)d_in[10];
    float* pred = (float*)d_out;

    // workspace layout (16B-aligned), total ~32.6 MB
    char* w = (char*)d_ws;
    int*            deg   = (int*)w;                               //     40,960 B
    int2*           ell   = (int2*)(w + 40960);                    // 10,485,760 B (10240 x 128 x 8)
    unsigned short* cat   = (unsigned short*)(w + 10526720);       // 10,354,688 B (M_PAD x 512)
    unsigned short* Wct   = (unsigned short*)(w + 20881408);       //    524,288 B
    unsigned short* W1t   = (unsigned short*)(w + 21405696);       //    524,288 B
    unsigned short* h     = (unsigned short*)(w + 21929984);       // 10,354,688 B (M_PAD x 512)
    float*          partb = (float*)(w + 32284672);                //    323,584 B (8 x M_PAD)

    // ---- zero slot counters ----
    k_zero<<<40, 256, 0, stream>>>(deg);

    // ---- fused prep (ELL scatter + cat_x + both weight transposes) ----
    k_prep<<<5798, 256, 0, stream>>>(esrc, edst, eval, deg, ell, x, cat, Wc, Wct, W1, W1t);

    // ---- gather-aggregate into cat second half ----
    k_agg<<<(N_NODES * 64 + 255) / 256, 256, 0, stream>>>(deg, ell, cat);

    // ---- tiled GEMMs: 79 M-tiles x 4 N-tiles = 316 blocks ----
    k_gemm128<0><<<316, 256, 0, stream>>>(cat, Wct, bc, nullptr, nullptr, h, nullptr);
    k_gemm128<1><<<316, 256, 0, stream>>>(h, W1t, b1, pa, W2, nullptr, partb);

    // ---- final partial reduce ----
    k_vout<<<(N_NODES + 255) / 256, 256, 0, stream>>>(partb, b2, pred);
}